// Round 7
// baseline (137.355 us; speedup 1.0000x reference)
//
#include <hip/hip_runtime.h>
#include <hip/hip_bf16.h>

#define TLEN 4096
#define NINP 256
#define DD   64

// 1/sqrt(64) * log2(e): folded into WqT so softmax = exp2(s)
#define QSCALE 0.18033688011112042f

typedef __attribute__((ext_vector_type(8))) short bf16x8;
typedef __attribute__((ext_vector_type(4))) short bf16x4;
typedef __attribute__((ext_vector_type(4))) float f32x4;

union U8 { bf16x8 v; uint u[4]; };
union U4 { bf16x4 v; uint u[2]; };

// fp32 -> bf16 RNE (manual; v_cvt_pk_bf16_f32 is NOT RNE -> 5x absmax blowup)
__device__ inline ushort bfu(float x) {
    union { float f; uint u; } a; a.f = x;
    uint r = a.u + 0x7fffu + ((a.u >> 16) & 1u);
    return (ushort)(r >> 16);
}
__device__ inline uint pk2(float lo, float hi) {
    return (uint)bfu(lo) | ((uint)bfu(hi) << 16);
}

__device__ inline bf16x8 ld16(const ushort* p) {  // 16B-aligned global/LDS
    return *(const bf16x8*)p;
}
__device__ inline bf16x8 ld8x2(const ushort* p) { // 8B-aligned (padded LDS)
    U8 u;
    uint2 a = *(const uint2*)p;
    uint2 b = *(const uint2*)(p + 4);
    u.u[0] = a.x; u.u[1] = a.y; u.u[2] = b.x; u.u[3] = b.y;
    return u.v;
}

// ---------------------------------------------------------------------------
// prep: WT[m][d][k] = W_m[k][d] as bf16 (Wq scaled by QSCALE). LDS transpose.
// ---------------------------------------------------------------------------
__global__ __launch_bounds__(256) void prep_wt(
    const float* __restrict__ Wq, const float* __restrict__ Wk,
    const float* __restrict__ Wv, ushort* __restrict__ WT)
{
    __shared__ ushort lt[256 * 66];   // [k][d] padded
    const int t = threadIdx.x;
    const int m = blockIdx.x;
    const float* W = (m == 0) ? Wq : ((m == 1) ? Wk : Wv);
    const float scale = (m == 0) ? QSCALE : 1.0f;

    #pragma unroll
    for (int j = 0; j < 16; ++j) {
        int i4 = t + 256 * j;                 // float4 index
        float4 v = *(const float4*)&W[i4 * 4];
        int k = i4 >> 4, d = (i4 * 4) & 63;
        *(uint*)&lt[k * 66 + d]     = pk2(v.x * scale, v.y * scale);
        *(uint*)&lt[k * 66 + d + 2] = pk2(v.z * scale, v.w * scale);
    }
    __syncthreads();
    #pragma unroll
    for (int j = 0; j < 32; ++j) {            // uint (2-key) stores
        int o2 = t + 256 * j;
        int d = o2 >> 7, k = (o2 & 127) * 2;
        uint pk = (uint)lt[k * 66 + d] | ((uint)lt[(k + 1) * 66 + d] << 16);
        *(uint*)&WT[m * 16384 + d * 256 + k] = pk;
    }
}

// ---------------------------------------------------------------------------
// QKV: m-split grid (3 x rowblocks), 256 threads, 64 rows/block. Each block
// stages only its own 32KB W panel -> 43KB LDS -> 3 blocks/CU (3 waves/SIMD).
// mb=0: Q row-major, mb=1: K row-major, mb=2: VhT[d][t] via LDS repack.
// ---------------------------------------------------------------------------
__global__ __launch_bounds__(256, 3) void qkv_kernel(
    const float* __restrict__ y, const ushort* __restrict__ WT,
    ushort* __restrict__ Qh, ushort* __restrict__ Kh, ushort* __restrict__ VhT,
    const int rbn)
{
    __shared__ ushort Wl[64 * 268];   // 34,304 B (pad 268: ~2-way banks)
    __shared__ ushort tb[64 * 68];    //  8,704 B

    const int t = threadIdx.x;
    const int w = t >> 6, lane = t & 63;
    const int quad = lane >> 4, l15 = lane & 15;
    const int mb = blockIdx.x / rbn;       // 0=Q 1=K 2=V
    const int rb = blockIdx.x % rbn;
    const int rowbase = rb * 64;
    const int myrow = rowbase + w * 16 + l15;

    // ---- stage WT[mb] (32 KB): thread -> row n=t>>2, 128B segment ----
    {
        int n = t >> 2, seg = t & 3;
        const ushort* src = WT + mb * 16384 + n * 256 + seg * 64;
        ushort* dst = &Wl[n * 268 + seg * 64];
        #pragma unroll
        for (int j = 0; j < 16; ++j)
            ((uint2*)dst)[j] = ((const uint2*)src)[j];
    }

    // ---- A-fragments (overlap with staging loads) ----
    bf16x8 afrag[8];
    const float* yrow = y + (size_t)myrow * NINP;
    #pragma unroll
    for (int s = 0; s < 8; ++s) {
        float4 lo = *(const float4*)&yrow[s * 32 + quad * 8];
        float4 hi = *(const float4*)&yrow[s * 32 + quad * 8 + 4];
        U8 u;
        u.u[0] = pk2(lo.x, lo.y);
        u.u[1] = pk2(lo.z, lo.w);
        u.u[2] = pk2(hi.x, hi.y);
        u.u[3] = pk2(hi.z, hi.w);
        afrag[s] = u.v;
    }

    __syncthreads();

    f32x4 acc[4];
    #pragma unroll
    for (int nt = 0; nt < 4; ++nt) acc[nt] = f32x4{0.f, 0.f, 0.f, 0.f};

    #pragma unroll
    for (int s = 0; s < 8; ++s)
        #pragma unroll
        for (int nt = 0; nt < 4; ++nt) {
            bf16x8 bfrag = ld8x2(&Wl[(nt * 16 + l15) * 268 + s * 32 + quad * 8]);
            acc[nt] = __builtin_amdgcn_mfma_f32_16x16x32_bf16(
                afrag[s], bfrag, acc[nt], 0, 0, 0);
        }

    if (mb < 2) {
        // ---- store Q or K (row-major bf16) via LDS repack ----
        #pragma unroll
        for (int nt = 0; nt < 4; ++nt)
            #pragma unroll
            for (int r = 0; r < 4; ++r)
                tb[(w * 16 + quad * 4 + r) * 68 + nt * 16 + l15] = bfu(acc[nt][r]);
        __syncthreads();
        int row = t >> 2, seg = t & 3;
        ushort* gd = (mb == 0 ? Qh : Kh) + (size_t)(rowbase + row) * DD + seg * 16;
        const ushort* sp = &tb[row * 68 + seg * 16];
        #pragma unroll
        for (int j = 0; j < 4; ++j) ((uint2*)gd)[j] = ((const uint2*)sp)[j];
    } else {
        // ---- store VhT[d][t] ----
        #pragma unroll
        for (int nt = 0; nt < 4; ++nt) {
            int d = nt * 16 + l15;
            #pragma unroll
            for (int r = 0; r < 4; r += 2) {
                int tt = w * 16 + quad * 4 + r;
                *(uint*)&tb[d * 68 + tt] = pk2(acc[nt][r], acc[nt][r + 1]);
            }
        }
        __syncthreads();
        int d = t >> 2, seg = t & 3;
        int bb = rb >> 6;                           // batch (64 rowblocks/batch)
        int tcol = (rb & 63) * 64 + seg * 16;
        ushort* gv = VhT + ((size_t)bb * DD + d) * TLEN + tcol;
        const ushort* sp = &tb[d * 68 + seg * 16];
        #pragma unroll
        for (int j = 0; j < 4; ++j) ((uint2*)gv)[j] = ((const uint2*)sp)[j];
    }
}

// ===========================================================================
// Attention helpers (R7): ping-pong double-buffered K and V fragments.
// Rationale: 512-thr blocks can never be 2/CU (combined arch+acc VGPR ~168
// -> 3 waves/SIMD; a 2nd 8-wave block needs 4). So registers up to 256 are
// FREE -> spend on prefetch depth: loads for chunk i+1 issue at top of
// chunk i -> full-chunk (~2.4k cyc) latency cover for K AND V (was ~0.4).
// ===========================================================================
__device__ inline void load_k(bf16x8 (&kf)[4][2], const ushort* __restrict__ Kb,
                              int c0, int l15, int quad)
{
    #pragma unroll
    for (int kt = 0; kt < 4; ++kt)
        #pragma unroll
        for (int s = 0; s < 2; ++s)
            kf[kt][s] = ld16(Kb + (size_t)(c0 + kt * 16 + l15) * DD + s * 32 + quad * 8);
}

__device__ inline void load_v(U4 (&vt)[4][4], const ushort* const (&vbase)[4], int c0)
{
    #pragma unroll
    for (int nt = 0; nt < 4; ++nt)
        #pragma unroll
        for (int kt = 0; kt < 4; ++kt) {
            uint2 vv = *(const uint2*)(vbase[nt] + c0 + kt * 16);
            vt[nt][kt].u[0] = vv.x; vt[nt][kt].u[1] = vv.y;
        }
}

__device__ inline void attn_chunk(
    const bf16x8 (&kf)[4][2], const U4 (&vt)[4][4], const bf16x8 (&qf)[2][2],
    f32x4 (&oT)[2][4], float (&l_acc)[2],
    int c0, int qb, int quad, int l15)
{
    // S^T = K·Q^T
    f32x4 st[2][4];
    #pragma unroll
    for (int qt = 0; qt < 2; ++qt)
        #pragma unroll
        for (int kt = 0; kt < 4; ++kt)
            st[qt][kt] = f32x4{0.f, 0.f, 0.f, 0.f};
    __builtin_amdgcn_s_setprio(1);
    #pragma unroll
    for (int s = 0; s < 2; ++s)
        #pragma unroll
        for (int qt = 0; qt < 2; ++qt)
            #pragma unroll
            for (int kt = 0; kt < 4; ++kt)
                st[qt][kt] = __builtin_amdgcn_mfma_f32_16x16x32_bf16(
                    kf[kt][s], qf[qt][s], st[qt][kt], 0, 0, 0);
    __builtin_amdgcn_s_setprio(0);

    // softmax weights -> bf16 P^T frags, in-register (scale folded into Wq)
    U4 pa[2][4];
    if (c0 + 63 <= qb) {            // wave-uniform: fully unmasked chunk
        #pragma unroll
        for (int qt = 0; qt < 2; ++qt)
            #pragma unroll
            for (int kt = 0; kt < 4; ++kt) {
                float p0 = exp2f(st[qt][kt][0]);
                float p1 = exp2f(st[qt][kt][1]);
                float p2 = exp2f(st[qt][kt][2]);
                float p3 = exp2f(st[qt][kt][3]);
                l_acc[qt] += (p0 + p1) + (p2 + p3);
                pa[qt][kt].u[0] = pk2(p0, p1);
                pa[qt][kt].u[1] = pk2(p2, p3);
            }
    } else {                        // diagonal chunk: causal mask
        #pragma unroll
        for (int qt = 0; qt < 2; ++qt) {
            const int q = qb + qt * 16 + l15;
            #pragma unroll
            for (int kt = 0; kt < 4; ++kt) {
                const int kb0 = c0 + kt * 16 + quad * 4;
                float p[4];
                #pragma unroll
                for (int r = 0; r < 4; ++r) {
                    float e = exp2f(st[qt][kt][r]);
                    p[r] = (kb0 + r <= q) ? e : 0.f;
                    l_acc[qt] += p[r];
                }
                pa[qt][kt].u[0] = pk2(p[0], p[1]);
                pa[qt][kt].u[1] = pk2(p[2], p[3]);
            }
        }
    }

    // O^T += V^T · P^T   (16x16x16, K=16: B-layout == S^T lane layout)
    __builtin_amdgcn_s_setprio(1);
    #pragma unroll
    for (int qt = 0; qt < 2; ++qt)
        #pragma unroll
        for (int nt = 0; nt < 4; ++nt)
            #pragma unroll
            for (int kt = 0; kt < 4; ++kt)
                oT[qt][nt] = __builtin_amdgcn_mfma_f32_16x16x16bf16_1k(
                    vt[nt][kt].v, pa[qt][kt].v, oT[qt][nt], 0, 0, 0);
    __builtin_amdgcn_s_setprio(0);
}

// ---------------------------------------------------------------------------
// Attention: 512 blocks x 512 threads, ONE complete tile per block (8-way
// key-seg split -> complete in-block combine). XCD-batch clustering:
// batch=(id&7)>>1 -> 4MB K+V per XCD = L2-resident. Pair-balanced tile
// decode (CU k of an XCD gets tiles j0 and 127-j0 under breadth-first
// dispatch). Inner loop: 2x-unrolled ping-pong prefetch (kfA/B, vtA/B) --
// statically indexed buffers (rule #20), full-chunk latency cover.
// ---------------------------------------------------------------------------
__global__ __launch_bounds__(512, 2) void attn_kernel(
    const ushort* __restrict__ Qh, const ushort* __restrict__ Kh,
    const ushort* __restrict__ VhT, float* __restrict__ out)
{
    __shared__ float Ob[8][32 * 68];    // per-wave partial O [q][d] padded
    __shared__ float lb[8][32];         // per-wave partial l

    const int t = threadIdx.x;
    const int w = t >> 6, lane = t & 63;
    const int quad = lane >> 4, l15 = lane & 15;

    // XCD-clustered, pair-balanced decode (grid = 512, 8 XCDs, 4 batches)
    const int x  = blockIdx.x & 7;
    const int b  = x >> 1;
    const int r_ = (int)blockIdx.x >> 3;          // 0..63
    const int h  = r_ >> 5;                       // pair half
    const int j0 = ((r_ & 31) << 1) | (x & 1);    // 0..63
    const int tile = h ? (127 - j0) : j0;

    const int seg = w;
    const int qb  = tile * 32;
    const int nc  = (tile + 2) >> 1;              // 64-key chunks (masked tail)
    const int cps = (nc + 7) >> 3;
    const int clo = seg * cps;
    const int chi = (nc < clo + cps) ? nc : (clo + cps);

    const ushort* Qb = Qh + (size_t)b * TLEN * DD;
    const ushort* Kb = Kh + (size_t)b * TLEN * DD;
    const ushort* Vb = VhT + (size_t)b * DD * TLEN;
    float* outb = out + (size_t)b * TLEN * DD;

    f32x4 oT[2][4];                      // O^T: d=nt*16+quad*4+r, q=qb+qt*16+l15
    #pragma unroll
    for (int qt = 0; qt < 2; ++qt)
        #pragma unroll
        for (int nt = 0; nt < 4; ++nt)
            oT[qt][nt] = f32x4{0.f, 0.f, 0.f, 0.f};
    float l_acc[2] = {0.f, 0.f};

    if (clo < chi) {
        // Q B-frags (fixed per tile)
        bf16x8 qf[2][2];
        #pragma unroll
        for (int qt = 0; qt < 2; ++qt)
            #pragma unroll
            for (int s = 0; s < 2; ++s)
                qf[qt][s] = ld16(Qb + (size_t)(qb + qt * 16 + l15) * DD + s * 32 + quad * 8);

        // per-lane V^T base pointers (row = d = nt*16+l15, k-offset = quad*4)
        const ushort* vbase[4];
        #pragma unroll
        for (int nt = 0; nt < 4; ++nt)
            vbase[nt] = Vb + (size_t)(nt * 16 + l15) * TLEN + quad * 4;

        // ping-pong buffers
        bf16x8 kfA[4][2], kfB[4][2];
        U4 vtA[4][4], vtB[4][4];

        // prologue: fill A for first chunk
        load_v(vtA, vbase, clo * 64);
        load_k(kfA, Kb, clo * 64, l15, quad);

        for (int ci = clo; ci < chi; ci += 2) {
            // ---- body A: prefetch ci+1 into B, compute ci from A ----
            {
                const int c0 = ci * 64;
                if (ci + 1 < chi) {
                    load_v(vtB, vbase, c0 + 64);
                    load_k(kfB, Kb, c0 + 64, l15, quad);
                }
                attn_chunk(kfA, vtA, qf, oT, l_acc, c0, qb, quad, l15);
            }
            // ---- body B: prefetch ci+2 into A, compute ci+1 from B ----
            if (ci + 1 < chi) {
                const int c0 = (ci + 1) * 64;
                if (ci + 2 < chi) {
                    load_v(vtA, vbase, c0 + 64);
                    load_k(kfA, Kb, c0 + 64, l15, quad);
                }
                attn_chunk(kfB, vtB, qf, oT, l_acc, c0, qb, quad, l15);
            }
        }

        // reduce l across quads (keys live in quads)
        #pragma unroll
        for (int qt = 0; qt < 2; ++qt) {
            l_acc[qt] += __shfl_xor(l_acc[qt], 16, 64);
            l_acc[qt] += __shfl_xor(l_acc[qt], 32, 64);
        }
    }

    // publish partials (zeros if empty task)
    #pragma unroll
    for (int qt = 0; qt < 2; ++qt) {
        #pragma unroll
        for (int nt = 0; nt < 4; ++nt)
            #pragma unroll
            for (int r = 0; r < 4; ++r)
                Ob[w][(qt * 16 + l15) * 68 + nt * 16 + quad * 4 + r] = oT[qt][nt][r];
        if (quad == 0) lb[w][qt * 16 + l15] = l_acc[qt];
    }
    __syncthreads();

    // in-block combine + store (complete: all 8 segs of this tile here)
    #pragma unroll
    for (int e = 0; e < 4; ++e) {
        int idx = t + 512 * e;
        int q = idx >> 6, d = idx & 63;
        float s = 0.f, ls = 0.f;
        #pragma unroll
        for (int ww = 0; ww < 8; ++ww) {
            s += Ob[ww][q * 68 + d];
            ls += lb[ww][q];
        }
        outb[(size_t)(qb + q) * DD + d] = s * __builtin_amdgcn_rcpf(ls);
    }
}

extern "C" void kernel_launch(void* const* d_in, const int* in_sizes, int n_in,
                              void* d_out, int out_size, void* d_ws, size_t ws_size,
                              hipStream_t stream) {
    const float* y  = (const float*)d_in[0];
    const float* Wq = (const float*)d_in[1];
    const float* Wk = (const float*)d_in[2];
    const float* Wv = (const float*)d_in[3];
    float* outp = (float*)d_out;

    const int rows = in_sizes[0] / NINP;       // B*T = 16384
    const int nb = rows / TLEN;                // batches = 4
    const int rbn = rows / 64;                 // 256 row-blocks

    ushort* WT  = (ushort*)d_ws;               // 3*16384 bf16 = 96 KB
    ushort* Qh  = WT + 3 * 16384;              // rows*64 bf16 = 2 MB
    ushort* Kh  = Qh + (size_t)rows * DD;
    ushort* VhT = Kh + (size_t)rows * DD;      // [b][d][t]

    prep_wt<<<3, 256, 0, stream>>>(Wq, Wk, Wv, WT);
    qkv_kernel<<<3 * rbn, 256, 0, stream>>>(y, WT, Qh, Kh, VhT, rbn);
    attn_kernel<<<nb * 128, 512, 0, stream>>>(Qh, Kh, VhT, outp);
}

// Round 8
// 103.421 us; speedup vs baseline: 1.3281x; 1.3281x over previous
//
#include <hip/hip_runtime.h>
#include <hip/hip_bf16.h>

#define TLEN 4096
#define NINP 256
#define DD   64

// 1/sqrt(64) * log2(e): folded into WqT so softmax = exp2(s)
#define QSCALE 0.18033688011112042f

typedef __attribute__((ext_vector_type(8))) short bf16x8;
typedef __attribute__((ext_vector_type(4))) short bf16x4;
typedef __attribute__((ext_vector_type(4))) float f32x4;

union U8 { bf16x8 v; uint u[4]; };
union U4 { bf16x4 v; uint u[2]; };

// fp32 -> bf16 RNE (manual; v_cvt_pk_bf16_f32 is NOT RNE -> 5x absmax blowup)
__device__ inline ushort bfu(float x) {
    union { float f; uint u; } a; a.f = x;
    uint r = a.u + 0x7fffu + ((a.u >> 16) & 1u);
    return (ushort)(r >> 16);
}
__device__ inline uint pk2(float lo, float hi) {
    return (uint)bfu(lo) | ((uint)bfu(hi) << 16);
}

__device__ inline bf16x8 ld16(const ushort* p) {  // 16B-aligned global/LDS
    return *(const bf16x8*)p;
}
__device__ inline bf16x8 ld8x2(const ushort* p) { // 8B-aligned (padded LDS)
    U8 u;
    uint2 a = *(const uint2*)p;
    uint2 b = *(const uint2*)(p + 4);
    u.u[0] = a.x; u.u[1] = a.y; u.u[2] = b.x; u.u[3] = b.y;
    return u.v;
}

// ---------------------------------------------------------------------------
// prep: WT[m][d][k] = W_m[k][d] as bf16 (Wq scaled by QSCALE). LDS transpose.
// ---------------------------------------------------------------------------
__global__ __launch_bounds__(256) void prep_wt(
    const float* __restrict__ Wq, const float* __restrict__ Wk,
    const float* __restrict__ Wv, ushort* __restrict__ WT)
{
    __shared__ ushort lt[256 * 66];   // [k][d] padded
    const int t = threadIdx.x;
    const int m = blockIdx.x;
    const float* W = (m == 0) ? Wq : ((m == 1) ? Wk : Wv);
    const float scale = (m == 0) ? QSCALE : 1.0f;

    #pragma unroll
    for (int j = 0; j < 16; ++j) {
        int i4 = t + 256 * j;                 // float4 index
        float4 v = *(const float4*)&W[i4 * 4];
        int k = i4 >> 4, d = (i4 * 4) & 63;
        *(uint*)&lt[k * 66 + d]     = pk2(v.x * scale, v.y * scale);
        *(uint*)&lt[k * 66 + d + 2] = pk2(v.z * scale, v.w * scale);
    }
    __syncthreads();
    #pragma unroll
    for (int j = 0; j < 32; ++j) {            // uint (2-key) stores
        int o2 = t + 256 * j;
        int d = o2 >> 7, k = (o2 & 127) * 2;
        uint pk = (uint)lt[k * 66 + d] | ((uint)lt[(k + 1) * 66 + d] << 16);
        *(uint*)&WT[m * 16384 + d * 256 + k] = pk;
    }
}

// ---------------------------------------------------------------------------
// QKV: m-split grid (3 x rowblocks), 256 threads, 64 rows/block, 43KB LDS ->
// 3 blocks/CU. mb=0: Q row-major. mb=1/2: K/V written in FRAG-NATIVE PACKED
// layout: per 64-key chunk, 8KB where attn's load j reads lanes' 16B
// contiguously (addr = chunk*8KB + j*1KB + lane*16B) -> attn loads become
// fully-coalesced sequential streams (R8: kills the scattered-8B V pattern).
// ---------------------------------------------------------------------------
__global__ __launch_bounds__(256, 3) void qkv_kernel(
    const float* __restrict__ y, const ushort* __restrict__ WT,
    ushort* __restrict__ Qh, ushort* __restrict__ Kp, ushort* __restrict__ Vp,
    const int rbn)
{
    __shared__ ushort Wl[64 * 268];   // 34,304 B (pad 268: ~2-way banks)
    __shared__ ushort tb[64 * 68];    //  8,704 B

    const int t = threadIdx.x;
    const int w = t >> 6, lane = t & 63;
    const int quad = lane >> 4, l15 = lane & 15;
    const int mb = blockIdx.x / rbn;       // 0=Q 1=K 2=V
    const int rb = blockIdx.x % rbn;       // rowblock == (batch*64 + chunk)
    const int rowbase = rb * 64;
    const int myrow = rowbase + w * 16 + l15;

    // ---- stage WT[mb] (32 KB): thread -> row n=t>>2, 128B segment ----
    {
        int n = t >> 2, seg = t & 3;
        const ushort* src = WT + mb * 16384 + n * 256 + seg * 64;
        ushort* dst = &Wl[n * 268 + seg * 64];
        #pragma unroll
        for (int j = 0; j < 16; ++j)
            ((uint2*)dst)[j] = ((const uint2*)src)[j];
    }

    // ---- A-fragments (overlap with staging loads) ----
    bf16x8 afrag[8];
    const float* yrow = y + (size_t)myrow * NINP;
    #pragma unroll
    for (int s = 0; s < 8; ++s) {
        float4 lo = *(const float4*)&yrow[s * 32 + quad * 8];
        float4 hi = *(const float4*)&yrow[s * 32 + quad * 8 + 4];
        U8 u;
        u.u[0] = pk2(lo.x, lo.y);
        u.u[1] = pk2(lo.z, lo.w);
        u.u[2] = pk2(hi.x, hi.y);
        u.u[3] = pk2(hi.z, hi.w);
        afrag[s] = u.v;
    }

    __syncthreads();

    f32x4 acc[4];
    #pragma unroll
    for (int nt = 0; nt < 4; ++nt) acc[nt] = f32x4{0.f, 0.f, 0.f, 0.f};

    #pragma unroll
    for (int s = 0; s < 8; ++s)
        #pragma unroll
        for (int nt = 0; nt < 4; ++nt) {
            bf16x8 bfrag = ld8x2(&Wl[(nt * 16 + l15) * 268 + s * 32 + quad * 8]);
            acc[nt] = __builtin_amdgcn_mfma_f32_16x16x32_bf16(
                afrag[s], bfrag, acc[nt], 0, 0, 0);
        }

    if (mb == 0) {
        // ---- Q row-major via LDS repack (unchanged) ----
        #pragma unroll
        for (int nt = 0; nt < 4; ++nt)
            #pragma unroll
            for (int r = 0; r < 4; ++r)
                tb[(w * 16 + quad * 4 + r) * 68 + nt * 16 + l15] = bfu(acc[nt][r]);
        __syncthreads();
        int row = t >> 2, seg = t & 3;
        ushort* gd = Qh + (size_t)(rowbase + row) * DD + seg * 16;
        const ushort* sp = &tb[row * 68 + seg * 16];
        #pragma unroll
        for (int j = 0; j < 4; ++j) ((uint2*)gd)[j] = ((const uint2*)sp)[j];
    } else if (mb == 1) {
        // ---- K packed: tb[row][d] (as before), then frag-native store.
        // attn kf[kt][s]: lane(quad,l15) needs K[row=kt*16+l15][d=s*32+quad*8..+7]
        // unit idx = (kt*2+s)*64 + lane -> 16B from tb[row*68 + dcol].
        #pragma unroll
        for (int nt = 0; nt < 4; ++nt)
            #pragma unroll
            for (int r = 0; r < 4; ++r)
                tb[(w * 16 + quad * 4 + r) * 68 + nt * 16 + l15] = bfu(acc[nt][r]);
        __syncthreads();
        #pragma unroll
        for (int j = 0; j < 2; ++j) {
            int idx = t + 256 * j;                 // 16B-unit 0..511
            int instr = idx >> 6, ln = idx & 63;
            int kt = instr >> 1, s = instr & 1;
            int q2 = ln >> 4, l15b = ln & 15;
            int row = kt * 16 + l15b, dcol = s * 32 + q2 * 8;
            const ushort* sp = &tb[row * 68 + dcol];
            ushort* gd = Kp + (size_t)rb * 4096 + idx * 8;
            ((uint2*)gd)[0] = ((const uint2*)sp)[0];
            ((uint2*)gd)[1] = ((const uint2*)sp)[1];
        }
    } else {
        // ---- V packed: tb[d][tt] (as before), then frag-native store.
        // attn vt[nt][2m+e]: lane(quad,l15) needs V^T[d=nt*16+l15][k=(2m+e)*16+quad*4..+3]
        // unit idx = (nt*2+m)*64 + lane -> two 8B halves e=0,1.
        #pragma unroll
        for (int nt = 0; nt < 4; ++nt) {
            int d = nt * 16 + l15;
            #pragma unroll
            for (int r = 0; r < 4; r += 2) {
                int tt = w * 16 + quad * 4 + r;
                *(uint*)&tb[d * 68 + tt] = pk2(acc[nt][r], acc[nt][r + 1]);
            }
        }
        __syncthreads();
        #pragma unroll
        for (int j = 0; j < 2; ++j) {
            int idx = t + 256 * j;                 // 16B-unit 0..511
            int instr = idx >> 6, ln = idx & 63;
            int nt = instr >> 1, m = instr & 1;
            int q2 = ln >> 4, l15b = ln & 15;
            int d = nt * 16 + l15b;
            int k0 = 32 * m + q2 * 4;
            ushort* gd = Vp + (size_t)rb * 4096 + idx * 8;
            ((uint2*)gd)[0] = *(const uint2*)&tb[d * 68 + k0];
            ((uint2*)gd)[1] = *(const uint2*)&tb[d * 68 + k0 + 16];
        }
    }
}

// ===========================================================================
// Attention helpers (R8): packed-layout loads. Per chunk: 8 K + 8 V fully
// coalesced dwordx4 (lane*16B contiguous), vs 24 scattered instrs / 384
// line-transactions before. R7's ping-pong REVERTED (spilled: VGPR budget
// is ~full incl acc-VGPRs; any change must be VGPR-neutral).
// ===========================================================================
__device__ inline void load_k(bf16x8 (&kf)[4][2], const ushort* __restrict__ Kpb,
                              int ci, int lane)
{
    const ushort* base = Kpb + (size_t)ci * 4096 + lane * 8;
    #pragma unroll
    for (int kt = 0; kt < 4; ++kt)
        #pragma unroll
        for (int s = 0; s < 2; ++s)
            kf[kt][s] = ld16(base + (kt * 2 + s) * 512);
}

__device__ inline void load_v(U4 (&vt)[4][4], const ushort* __restrict__ Vpb,
                              int ci, int lane)
{
    const ushort* base = Vpb + (size_t)ci * 4096 + lane * 8;
    #pragma unroll
    for (int nt = 0; nt < 4; ++nt)
        #pragma unroll
        for (int m = 0; m < 2; ++m) {
            U8 uu; uu.v = ld16(base + (nt * 2 + m) * 512);
            vt[nt][2 * m].u[0]     = uu.u[0];
            vt[nt][2 * m].u[1]     = uu.u[1];
            vt[nt][2 * m + 1].u[0] = uu.u[2];
            vt[nt][2 * m + 1].u[1] = uu.u[3];
        }
}

// ---------------------------------------------------------------------------
// Attention: 512 blocks x 512 threads, ONE complete tile per block (8-way
// key-seg split -> complete in-block combine). XCD-batch clustering:
// batch=(id&7)>>1 -> K+V per XCD pair L2-resident. Pair-balanced tile decode.
// S^T = K·Q^T (16x16x32); P stays IN REGISTERS (S^T lane layout == B-operand
// of mfma_f32_16x16x16_bf16) -> O^T = V^T·P^T, no LDS transpose.
// ---------------------------------------------------------------------------
__global__ __launch_bounds__(512, 2) void attn_kernel(
    const ushort* __restrict__ Qh, const ushort* __restrict__ Kp,
    const ushort* __restrict__ Vp, float* __restrict__ out)
{
    __shared__ float Ob[8][32 * 68];    // per-wave partial O [q][d] padded
    __shared__ float lb[8][32];         // per-wave partial l

    const int t = threadIdx.x;
    const int w = t >> 6, lane = t & 63;
    const int quad = lane >> 4, l15 = lane & 15;

    // XCD-clustered, pair-balanced decode (grid = 512, 8 XCDs, 4 batches)
    const int x  = blockIdx.x & 7;
    const int b  = x >> 1;
    const int r_ = (int)blockIdx.x >> 3;          // 0..63
    const int h  = r_ >> 5;                       // pair half
    const int j0 = ((r_ & 31) << 1) | (x & 1);    // 0..63
    const int tile = h ? (127 - j0) : j0;

    const int seg = w;
    const int qb  = tile * 32;
    const int nc  = (tile + 2) >> 1;              // 64-key chunks (masked tail)
    const int cps = (nc + 7) >> 3;
    const int clo = seg * cps;
    const int chi = (nc < clo + cps) ? nc : (clo + cps);

    const ushort* Qb  = Qh + (size_t)b * TLEN * DD;
    const ushort* Kpb = Kp + (size_t)b * 64 * 4096;
    const ushort* Vpb = Vp + (size_t)b * 64 * 4096;
    float* outb = out + (size_t)b * TLEN * DD;

    f32x4 oT[2][4];                      // O^T: d=nt*16+quad*4+r, q=qb+qt*16+l15
    #pragma unroll
    for (int qt = 0; qt < 2; ++qt)
        #pragma unroll
        for (int nt = 0; nt < 4; ++nt)
            oT[qt][nt] = f32x4{0.f, 0.f, 0.f, 0.f};
    float l_acc[2] = {0.f, 0.f};

    if (clo < chi) {
        // Q B-frags (fixed per tile)
        bf16x8 qf[2][2];
        #pragma unroll
        for (int qt = 0; qt < 2; ++qt)
            #pragma unroll
            for (int s = 0; s < 2; ++s)
                qf[qt][s] = ld16(Qb + (size_t)(qb + qt * 16 + l15) * DD + s * 32 + quad * 8);

        // K prefetch for first chunk
        bf16x8 kf[4][2];
        load_k(kf, Kpb, clo, lane);

        for (int ci = clo; ci < chi; ++ci) {
            const int c0 = ci * 64;

            // V frags (packed, coalesced; used ~end of body)
            U4 vt[4][4];
            load_v(vt, Vpb, ci, lane);

            // S^T = K·Q^T
            f32x4 st[2][4];
            #pragma unroll
            for (int qt = 0; qt < 2; ++qt)
                #pragma unroll
                for (int kt = 0; kt < 4; ++kt)
                    st[qt][kt] = f32x4{0.f, 0.f, 0.f, 0.f};
            __builtin_amdgcn_s_setprio(1);
            #pragma unroll
            for (int s = 0; s < 2; ++s)
                #pragma unroll
                for (int qt = 0; qt < 2; ++qt)
                    #pragma unroll
                    for (int kt = 0; kt < 4; ++kt)
                        st[qt][kt] = __builtin_amdgcn_mfma_f32_16x16x32_bf16(
                            kf[kt][s], qf[qt][s], st[qt][kt], 0, 0, 0);
            __builtin_amdgcn_s_setprio(0);

            // prefetch next chunk's K frags
            if (ci + 1 < chi) load_k(kf, Kpb, ci + 1, lane);

            // softmax weights -> bf16 P^T frags, in-register
            U4 pa[2][4];
            if (c0 + 63 <= qb) {            // wave-uniform: fully unmasked chunk
                #pragma unroll
                for (int qt = 0; qt < 2; ++qt)
                    #pragma unroll
                    for (int kt = 0; kt < 4; ++kt) {
                        float p0 = exp2f(st[qt][kt][0]);
                        float p1 = exp2f(st[qt][kt][1]);
                        float p2 = exp2f(st[qt][kt][2]);
                        float p3 = exp2f(st[qt][kt][3]);
                        l_acc[qt] += (p0 + p1) + (p2 + p3);
                        pa[qt][kt].u[0] = pk2(p0, p1);
                        pa[qt][kt].u[1] = pk2(p2, p3);
                    }
            } else {                        // diagonal chunk: causal mask
                #pragma unroll
                for (int qt = 0; qt < 2; ++qt) {
                    const int q = qb + qt * 16 + l15;
                    #pragma unroll
                    for (int kt = 0; kt < 4; ++kt) {
                        const int kb0 = c0 + kt * 16 + quad * 4;
                        float p[4];
                        #pragma unroll
                        for (int r = 0; r < 4; ++r) {
                            float e = exp2f(st[qt][kt][r]);
                            p[r] = (kb0 + r <= q) ? e : 0.f;
                            l_acc[qt] += p[r];
                        }
                        pa[qt][kt].u[0] = pk2(p[0], p[1]);
                        pa[qt][kt].u[1] = pk2(p[2], p[3]);
                    }
                }
            }

            // O^T += V^T · P^T   (16x16x16, K=16: B-layout == S^T lane layout)
            __builtin_amdgcn_s_setprio(1);
            #pragma unroll
            for (int qt = 0; qt < 2; ++qt)
                #pragma unroll
                for (int nt = 0; nt < 4; ++nt)
                    #pragma unroll
                    for (int kt = 0; kt < 4; ++kt)
                        oT[qt][nt] = __builtin_amdgcn_mfma_f32_16x16x16bf16_1k(
                            vt[nt][kt].v, pa[qt][kt].v, oT[qt][nt], 0, 0, 0);
            __builtin_amdgcn_s_setprio(0);
        }

        // reduce l across quads (keys live in quads)
        #pragma unroll
        for (int qt = 0; qt < 2; ++qt) {
            l_acc[qt] += __shfl_xor(l_acc[qt], 16, 64);
            l_acc[qt] += __shfl_xor(l_acc[qt], 32, 64);
        }
    }

    // publish partials (zeros if empty task)
    #pragma unroll
    for (int qt = 0; qt < 2; ++qt) {
        #pragma unroll
        for (int nt = 0; nt < 4; ++nt)
            #pragma unroll
            for (int r = 0; r < 4; ++r)
                Ob[w][(qt * 16 + l15) * 68 + nt * 16 + quad * 4 + r] = oT[qt][nt][r];
        if (quad == 0) lb[w][qt * 16 + l15] = l_acc[qt];
    }
    __syncthreads();

    // in-block combine + store (complete: all 8 segs of this tile here)
    #pragma unroll
    for (int e = 0; e < 4; ++e) {
        int idx = t + 512 * e;
        int q = idx >> 6, d = idx & 63;
        float s = 0.f, ls = 0.f;
        #pragma unroll
        for (int ww = 0; ww < 8; ++ww) {
            s += Ob[ww][q * 68 + d];
            ls += lb[ww][q];
        }
        outb[(size_t)(qb + q) * DD + d] = s * __builtin_amdgcn_rcpf(ls);
    }
}

extern "C" void kernel_launch(void* const* d_in, const int* in_sizes, int n_in,
                              void* d_out, int out_size, void* d_ws, size_t ws_size,
                              hipStream_t stream) {
    const float* y  = (const float*)d_in[0];
    const float* Wq = (const float*)d_in[1];
    const float* Wk = (const float*)d_in[2];
    const float* Wv = (const float*)d_in[3];
    float* outp = (float*)d_out;

    const int rows = in_sizes[0] / NINP;       // B*T = 16384
    const int rbn = rows / 64;                 // 256 row-blocks

    ushort* WT = (ushort*)d_ws;                // 3*16384 bf16 = 96 KB
    ushort* Qh = WT + 3 * 16384;               // rows*64 bf16 = 2 MB
    ushort* Kp = Qh + (size_t)rows * DD;       // packed K: rb*4096 units
    ushort* Vp = Kp + (size_t)rows * DD;       // packed V: rb*4096 units

    prep_wt<<<3, 256, 0, stream>>>(Wq, Wk, Wv, WT);
    qkv_kernel<<<3 * rbn, 256, 0, stream>>>(y, WT, Qh, Kp, Vp, rbn);
    attn_kernel<<<rbn * 2, 512, 0, stream>>>(Qh, Kp, Vp, outp);
}

// Round 9
// 103.325 us; speedup vs baseline: 1.3293x; 1.0009x over previous
//
#include <hip/hip_runtime.h>
#include <hip/hip_bf16.h>

#define TLEN 4096
#define NINP 256
#define DD   64

// 1/sqrt(64) * log2(e): folded into WqT so softmax = exp2(s)
#define QSCALE 0.18033688011112042f

typedef __attribute__((ext_vector_type(8))) short bf16x8;
typedef __attribute__((ext_vector_type(4))) short bf16x4;
typedef __attribute__((ext_vector_type(4))) float f32x4;

union U8 { bf16x8 v; uint u[4]; };
union U4 { bf16x4 v; uint u[2]; };

// fp32 -> bf16 RNE (manual; v_cvt_pk_bf16_f32 is NOT RNE -> 5x absmax blowup)
__device__ inline ushort bfu(float x) {
    union { float f; uint u; } a; a.f = x;
    uint r = a.u + 0x7fffu + ((a.u >> 16) & 1u);
    return (ushort)(r >> 16);
}
__device__ inline uint pk2(float lo, float hi) {
    return (uint)bfu(lo) | ((uint)bfu(hi) << 16);
}

__device__ inline bf16x8 ld16(const ushort* p) {  // 16B-aligned global/LDS
    return *(const bf16x8*)p;
}
__device__ inline bf16x8 ld8x2(const ushort* p) { // 8B-aligned (padded LDS)
    U8 u;
    uint2 a = *(const uint2*)p;
    uint2 b = *(const uint2*)(p + 4);
    u.u[0] = a.x; u.u[1] = a.y; u.u[2] = b.x; u.u[3] = b.y;
    return u.v;
}

// ---------------------------------------------------------------------------
// prep: WT[m][d][k] = W_m[k][d] as bf16 (Wq scaled by QSCALE). LDS transpose.
// ---------------------------------------------------------------------------
__global__ __launch_bounds__(256) void prep_wt(
    const float* __restrict__ Wq, const float* __restrict__ Wk,
    const float* __restrict__ Wv, ushort* __restrict__ WT)
{
    __shared__ ushort lt[256 * 66];   // [k][d] padded
    const int t = threadIdx.x;
    const int m = blockIdx.x;
    const float* W = (m == 0) ? Wq : ((m == 1) ? Wk : Wv);
    const float scale = (m == 0) ? QSCALE : 1.0f;

    #pragma unroll
    for (int j = 0; j < 16; ++j) {
        int i4 = t + 256 * j;                 // float4 index
        float4 v = *(const float4*)&W[i4 * 4];
        int k = i4 >> 4, d = (i4 * 4) & 63;
        *(uint*)&lt[k * 66 + d]     = pk2(v.x * scale, v.y * scale);
        *(uint*)&lt[k * 66 + d + 2] = pk2(v.z * scale, v.w * scale);
    }
    __syncthreads();
    #pragma unroll
    for (int j = 0; j < 32; ++j) {            // uint (2-key) stores
        int o2 = t + 256 * j;
        int d = o2 >> 7, k = (o2 & 127) * 2;
        uint pk = (uint)lt[k * 66 + d] | ((uint)lt[(k + 1) * 66 + d] << 16);
        *(uint*)&WT[m * 16384 + d * 256 + k] = pk;
    }
}

// ---------------------------------------------------------------------------
// QKV: m-split grid (3 x rowblocks), 256 threads, 64 rows/block, 43KB LDS ->
// 3 blocks/CU. mb=0: Q row-major. mb=1/2: K/V written in FRAG-NATIVE PACKED
// layout: per 64-key chunk, 8KB where attn's load j reads lanes' 16B
// contiguously (addr = chunk*8KB + j*1KB + lane*16B) -> attn loads become
// fully-coalesced sequential streams.
// ---------------------------------------------------------------------------
__global__ __launch_bounds__(256, 3) void qkv_kernel(
    const float* __restrict__ y, const ushort* __restrict__ WT,
    ushort* __restrict__ Qh, ushort* __restrict__ Kp, ushort* __restrict__ Vp,
    const int rbn)
{
    __shared__ ushort Wl[64 * 268];   // 34,304 B (pad 268: ~2-way banks)
    __shared__ ushort tb[64 * 68];    //  8,704 B

    const int t = threadIdx.x;
    const int w = t >> 6, lane = t & 63;
    const int quad = lane >> 4, l15 = lane & 15;
    const int mb = blockIdx.x / rbn;       // 0=Q 1=K 2=V
    const int rb = blockIdx.x % rbn;       // rowblock == (batch*64 + chunk64)
    const int rowbase = rb * 64;
    const int myrow = rowbase + w * 16 + l15;

    // ---- stage WT[mb] (32 KB): thread -> row n=t>>2, 128B segment ----
    {
        int n = t >> 2, seg = t & 3;
        const ushort* src = WT + mb * 16384 + n * 256 + seg * 64;
        ushort* dst = &Wl[n * 268 + seg * 64];
        #pragma unroll
        for (int j = 0; j < 16; ++j)
            ((uint2*)dst)[j] = ((const uint2*)src)[j];
    }

    // ---- A-fragments (overlap with staging loads) ----
    bf16x8 afrag[8];
    const float* yrow = y + (size_t)myrow * NINP;
    #pragma unroll
    for (int s = 0; s < 8; ++s) {
        float4 lo = *(const float4*)&yrow[s * 32 + quad * 8];
        float4 hi = *(const float4*)&yrow[s * 32 + quad * 8 + 4];
        U8 u;
        u.u[0] = pk2(lo.x, lo.y);
        u.u[1] = pk2(lo.z, lo.w);
        u.u[2] = pk2(hi.x, hi.y);
        u.u[3] = pk2(hi.z, hi.w);
        afrag[s] = u.v;
    }

    __syncthreads();

    f32x4 acc[4];
    #pragma unroll
    for (int nt = 0; nt < 4; ++nt) acc[nt] = f32x4{0.f, 0.f, 0.f, 0.f};

    #pragma unroll
    for (int s = 0; s < 8; ++s)
        #pragma unroll
        for (int nt = 0; nt < 4; ++nt) {
            bf16x8 bfrag = ld8x2(&Wl[(nt * 16 + l15) * 268 + s * 32 + quad * 8]);
            acc[nt] = __builtin_amdgcn_mfma_f32_16x16x32_bf16(
                afrag[s], bfrag, acc[nt], 0, 0, 0);
        }

    if (mb == 0) {
        // ---- Q row-major via LDS repack ----
        #pragma unroll
        for (int nt = 0; nt < 4; ++nt)
            #pragma unroll
            for (int r = 0; r < 4; ++r)
                tb[(w * 16 + quad * 4 + r) * 68 + nt * 16 + l15] = bfu(acc[nt][r]);
        __syncthreads();
        int row = t >> 2, seg = t & 3;
        ushort* gd = Qh + (size_t)(rowbase + row) * DD + seg * 16;
        const ushort* sp = &tb[row * 68 + seg * 16];
        #pragma unroll
        for (int j = 0; j < 4; ++j) ((uint2*)gd)[j] = ((const uint2*)sp)[j];
    } else if (mb == 1) {
        // ---- K packed: unit idx=(kt*2+s)*64+lane holds 16B of
        // K[row=kt*16+l15][d=s*32+quad*8..+7] ----
        #pragma unroll
        for (int nt = 0; nt < 4; ++nt)
            #pragma unroll
            for (int r = 0; r < 4; ++r)
                tb[(w * 16 + quad * 4 + r) * 68 + nt * 16 + l15] = bfu(acc[nt][r]);
        __syncthreads();
        #pragma unroll
        for (int j = 0; j < 2; ++j) {
            int idx = t + 256 * j;                 // 16B-unit 0..511
            int instr = idx >> 6, ln = idx & 63;
            int kt = instr >> 1, s = instr & 1;
            int q2 = ln >> 4, l15b = ln & 15;
            int row = kt * 16 + l15b, dcol = s * 32 + q2 * 8;
            const ushort* sp = &tb[row * 68 + dcol];
            ushort* gd = Kp + (size_t)rb * 4096 + idx * 8;
            ((uint2*)gd)[0] = ((const uint2*)sp)[0];
            ((uint2*)gd)[1] = ((const uint2*)sp)[1];
        }
    } else {
        // ---- V packed: unit idx=(nt*2+m)*64+lane holds two 8B halves
        // V^T[d=nt*16+l15][k=32m+16e+quad*4..+3], e=0,1 ----
        #pragma unroll
        for (int nt = 0; nt < 4; ++nt) {
            int d = nt * 16 + l15;
            #pragma unroll
            for (int r = 0; r < 4; r += 2) {
                int tt = w * 16 + quad * 4 + r;
                *(uint*)&tb[d * 68 + tt] = pk2(acc[nt][r], acc[nt][r + 1]);
            }
        }
        __syncthreads();
        #pragma unroll
        for (int j = 0; j < 2; ++j) {
            int idx = t + 256 * j;                 // 16B-unit 0..511
            int instr = idx >> 6, ln = idx & 63;
            int nt = instr >> 1, m = instr & 1;
            int q2 = ln >> 4, l15b = ln & 15;
            int d = nt * 16 + l15b;
            int k0 = 32 * m + q2 * 4;
            ushort* gd = Vp + (size_t)rb * 4096 + idx * 8;
            ((uint2*)gd)[0] = *(const uint2*)&tb[d * 68 + k0];
            ((uint2*)gd)[1] = *(const uint2*)&tb[d * 68 + k0 + 16];
        }
    }
}

// ===========================================================================
// Attention helpers (R9): 32-KEY chunks. Halves per-wave register state
// (kf/vt/st/pa) so combined arch+acc VGPR ~125 <= 128 -> with
// __launch_bounds__(512,4) TWO 8-wave blocks co-reside per CU = 4 waves/SIMD
// (was 2 since R3; stall fraction ~60% was the occupancy ceiling).
// Packed layout decomposes: K chunk-32 = contiguous 2KB; V = 4 x 1KB.
// Per-key MFMA/VALU/load rates unchanged. CONTINGENCY: if VGPR_Count ~64 or
// WRITE_SIZE balloons (R5-style launch-bounds anomaly), revert to (512,2)+
// 64-key chunks.
// ===========================================================================
__device__ inline void load_k32(bf16x8 (&kf)[2][2], const ushort* __restrict__ Kw,
                                int ci)
{
    const ushort* base = Kw + (size_t)ci * 2048;
    #pragma unroll
    for (int kt = 0; kt < 2; ++kt)
        #pragma unroll
        for (int s = 0; s < 2; ++s)
            kf[kt][s] = ld16(base + (kt * 2 + s) * 512);
}

__device__ inline void load_v32(U4 (&vt)[4][2], const ushort* __restrict__ Vw,
                                int ci)
{
    const ushort* base = Vw + (size_t)(ci >> 1) * 4096 + (ci & 1) * 512;
    #pragma unroll
    for (int nt = 0; nt < 4; ++nt) {
        U8 uu; uu.v = ld16(base + nt * 1024);
        vt[nt][0].u[0] = uu.u[0]; vt[nt][0].u[1] = uu.u[1];
        vt[nt][1].u[0] = uu.u[2]; vt[nt][1].u[1] = uu.u[3];
    }
}

// ---------------------------------------------------------------------------
// Attention: 512 blocks x 512 threads, ONE complete tile per block (8-way
// 32-key-chunk split -> complete in-block combine). XCD-batch clustering:
// batch=(id&7)>>1 -> K+V per XCD pair L2-resident. Pair-balanced tile decode
// (CU gets tiles j0 and 127-j0 -> 129 chunk-32s constant). Exactly ONE
// masked (diagonal) chunk per tile. S^T = K·Q^T (16x16x32); P stays IN
// REGISTERS (S^T lane layout == B-operand of mfma_f32_16x16x16_bf16) ->
// O^T = V^T·P^T, no LDS transpose.
// ---------------------------------------------------------------------------
__global__ __launch_bounds__(512, 4) void attn_kernel(
    const ushort* __restrict__ Qh, const ushort* __restrict__ Kp,
    const ushort* __restrict__ Vp, float* __restrict__ out)
{
    __shared__ float Ob[8][32 * 68];    // per-wave partial O [q][d] padded
    __shared__ float lb[8][32];         // per-wave partial l

    const int t = threadIdx.x;
    const int w = t >> 6, lane = t & 63;
    const int quad = lane >> 4, l15 = lane & 15;

    // XCD-clustered, pair-balanced decode (grid = 512, 8 XCDs, 4 batches)
    const int x  = blockIdx.x & 7;
    const int b  = x >> 1;
    const int r_ = (int)blockIdx.x >> 3;          // 0..63
    const int h  = r_ >> 5;                       // pair half
    const int j0 = ((r_ & 31) << 1) | (x & 1);    // 0..63
    const int tile = h ? (127 - j0) : j0;

    const int seg = w;
    const int qb  = tile * 32;
    const int nc  = tile + 1;                     // 32-key chunks
    const int cps = (nc + 7) >> 3;
    const int clo = seg * cps;
    const int chi = (nc < clo + cps) ? nc : (clo + cps);

    const ushort* Qb = Qh + (size_t)b * TLEN * DD;
    const ushort* Kw = Kp + (size_t)b * 64 * 4096 + lane * 8;
    const ushort* Vw = Vp + (size_t)b * 64 * 4096 + lane * 8;
    float* outb = out + (size_t)b * TLEN * DD;

    f32x4 oT[2][4];                      // O^T: d=nt*16+quad*4+r, q=qb+qt*16+l15
    #pragma unroll
    for (int qt = 0; qt < 2; ++qt)
        #pragma unroll
        for (int nt = 0; nt < 4; ++nt)
            oT[qt][nt] = f32x4{0.f, 0.f, 0.f, 0.f};
    float l_acc[2] = {0.f, 0.f};

    if (clo < chi) {
        // Q B-frags (fixed per tile)
        bf16x8 qf[2][2];
        #pragma unroll
        for (int qt = 0; qt < 2; ++qt)
            #pragma unroll
            for (int s = 0; s < 2; ++s)
                qf[qt][s] = ld16(Qb + (size_t)(qb + qt * 16 + l15) * DD + s * 32 + quad * 8);

        // K prefetch for first chunk
        bf16x8 kf[2][2];
        load_k32(kf, Kw, clo);

        for (int ci = clo; ci < chi; ++ci) {
            const int c0 = ci * 32;

            // V frags (packed, coalesced; used ~end of body)
            U4 vt[4][2];
            load_v32(vt, Vw, ci);

            // S^T = K·Q^T
            f32x4 st[2][2];
            #pragma unroll
            for (int qt = 0; qt < 2; ++qt)
                #pragma unroll
                for (int kt = 0; kt < 2; ++kt)
                    st[qt][kt] = f32x4{0.f, 0.f, 0.f, 0.f};
            __builtin_amdgcn_s_setprio(1);
            #pragma unroll
            for (int s = 0; s < 2; ++s)
                #pragma unroll
                for (int qt = 0; qt < 2; ++qt)
                    #pragma unroll
                    for (int kt = 0; kt < 2; ++kt)
                        st[qt][kt] = __builtin_amdgcn_mfma_f32_16x16x32_bf16(
                            kf[kt][s], qf[qt][s], st[qt][kt], 0, 0, 0);
            __builtin_amdgcn_s_setprio(0);

            // prefetch next chunk's K frags
            if (ci + 1 < chi) load_k32(kf, Kw, ci + 1);

            // softmax weights -> bf16 P^T frags, in-register
            U4 pa[2][2];
            if (c0 + 31 <= qb) {            // wave-uniform: fully unmasked chunk
                #pragma unroll
                for (int qt = 0; qt < 2; ++qt)
                    #pragma unroll
                    for (int kt = 0; kt < 2; ++kt) {
                        float p0 = exp2f(st[qt][kt][0]);
                        float p1 = exp2f(st[qt][kt][1]);
                        float p2 = exp2f(st[qt][kt][2]);
                        float p3 = exp2f(st[qt][kt][3]);
                        l_acc[qt] += (p0 + p1) + (p2 + p3);
                        pa[qt][kt].u[0] = pk2(p0, p1);
                        pa[qt][kt].u[1] = pk2(p2, p3);
                    }
            } else {                        // diagonal chunk: causal mask
                #pragma unroll
                for (int qt = 0; qt < 2; ++qt) {
                    const int q = qb + qt * 16 + l15;
                    #pragma unroll
                    for (int kt = 0; kt < 2; ++kt) {
                        const int kb0 = c0 + kt * 16 + quad * 4;
                        float p[4];
                        #pragma unroll
                        for (int r = 0; r < 4; ++r) {
                            float e = exp2f(st[qt][kt][r]);
                            p[r] = (kb0 + r <= q) ? e : 0.f;
                            l_acc[qt] += p[r];
                        }
                        pa[qt][kt].u[0] = pk2(p[0], p[1]);
                        pa[qt][kt].u[1] = pk2(p[2], p[3]);
                    }
                }
            }

            // O^T += V^T · P^T   (16x16x16, K=16: B-layout == S^T lane layout)
            __builtin_amdgcn_s_setprio(1);
            #pragma unroll
            for (int qt = 0; qt < 2; ++qt)
                #pragma unroll
                for (int nt = 0; nt < 4; ++nt)
                    #pragma unroll
                    for (int kt = 0; kt < 2; ++kt)
                        oT[qt][nt] = __builtin_amdgcn_mfma_f32_16x16x16bf16_1k(
                            vt[nt][kt].v, pa[qt][kt].v, oT[qt][nt], 0, 0, 0);
            __builtin_amdgcn_s_setprio(0);
        }

        // reduce l across quads (keys live in quads)
        #pragma unroll
        for (int qt = 0; qt < 2; ++qt) {
            l_acc[qt] += __shfl_xor(l_acc[qt], 16, 64);
            l_acc[qt] += __shfl_xor(l_acc[qt], 32, 64);
        }
    }

    // publish partials (zeros if empty task)
    #pragma unroll
    for (int qt = 0; qt < 2; ++qt) {
        #pragma unroll
        for (int nt = 0; nt < 4; ++nt)
            #pragma unroll
            for (int r = 0; r < 4; ++r)
                Ob[w][(qt * 16 + l15) * 68 + nt * 16 + quad * 4 + r] = oT[qt][nt][r];
        if (quad == 0) lb[w][qt * 16 + l15] = l_acc[qt];
    }
    __syncthreads();

    // in-block combine + store (complete: all 8 segs of this tile here)
    #pragma unroll
    for (int e = 0; e < 4; ++e) {
        int idx = t + 512 * e;
        int q = idx >> 6, d = idx & 63;
        float s = 0.f, ls = 0.f;
        #pragma unroll
        for (int ww = 0; ww < 8; ++ww) {
            s += Ob[ww][q * 68 + d];
            ls += lb[ww][q];
        }
        outb[(size_t)(qb + q) * DD + d] = s * __builtin_amdgcn_rcpf(ls);
    }
}

extern "C" void kernel_launch(void* const* d_in, const int* in_sizes, int n_in,
                              void* d_out, int out_size, void* d_ws, size_t ws_size,
                              hipStream_t stream) {
    const float* y  = (const float*)d_in[0];
    const float* Wq = (const float*)d_in[1];
    const float* Wk = (const float*)d_in[2];
    const float* Wv = (const float*)d_in[3];
    float* outp = (float*)d_out;

    const int rows = in_sizes[0] / NINP;       // B*T = 16384
    const int rbn = rows / 64;                 // 256 row-blocks

    ushort* WT = (ushort*)d_ws;                // 3*16384 bf16 = 96 KB
    ushort* Qh = WT + 3 * 16384;               // rows*64 bf16 = 2 MB
    ushort* Kp = Qh + (size_t)rows * DD;       // packed K: rb*4096 units
    ushort* Vp = Kp + (size_t)rows * DD;       // packed V: rb*4096 units

    prep_wt<<<3, 256, 0, stream>>>(Wq, Wk, Wv, WT);
    qkv_kernel<<<3 * rbn, 256, 0, stream>>>(y, WT, Qh, Kp, Vp, rbn);
    attn_kernel<<<rbn * 2, 512, 0, stream>>>(Qh, Kp, Vp, outp);
}

// Round 10
// 101.437 us; speedup vs baseline: 1.3541x; 1.0186x over previous
//
#include <hip/hip_runtime.h>
#include <hip/hip_bf16.h>

#define TLEN 4096
#define NINP 256
#define DD   64

// 1/sqrt(64) * log2(e): folded into WqT so softmax = exp2(s)
#define QSCALE 0.18033688011112042f

typedef __attribute__((ext_vector_type(8))) short bf16x8;
typedef __attribute__((ext_vector_type(4))) short bf16x4;
typedef __attribute__((ext_vector_type(4))) float f32x4;

union U8 { bf16x8 v; uint u[4]; };
union U4 { bf16x4 v; uint u[2]; };

// fp32 -> bf16 RNE (manual; v_cvt_pk_bf16_f32 is NOT RNE -> used only where
// bias is cancelled: P-weights, which appear in numerator AND denominator)
__device__ inline ushort bfu(float x) {
    union { float f; uint u; } a; a.f = x;
    uint r = a.u + 0x7fffu + ((a.u >> 16) & 1u);
    return (ushort)(r >> 16);
}
__device__ inline uint pk2(float lo, float hi) {
    return (uint)bfu(lo) | ((uint)bfu(hi) << 16);
}
// hardware packed cvt (non-RNE): P-only (scale-invariance cancels bias)
__device__ inline uint cvtpk(float lo, float hi) {
    uint r;
    asm("v_cvt_pk_bf16_f32 %0, %1, %2" : "=v"(r) : "v"(lo), "v"(hi));
    return r;
}

__device__ inline bf16x8 ld16(const ushort* p) {  // 16B-aligned global/LDS
    return *(const bf16x8*)p;
}
__device__ inline bf16x8 ld8x2(const ushort* p) { // 8B-aligned (padded LDS)
    U8 u;
    uint2 a = *(const uint2*)p;
    uint2 b = *(const uint2*)(p + 4);
    u.u[0] = a.x; u.u[1] = a.y; u.u[2] = b.x; u.u[3] = b.y;
    return u.v;
}

// ---------------------------------------------------------------------------
// prep: WT[m][d][k] = W_m[k][d] as bf16 (Wq scaled by QSCALE). LDS transpose.
// ---------------------------------------------------------------------------
__global__ __launch_bounds__(256) void prep_wt(
    const float* __restrict__ Wq, const float* __restrict__ Wk,
    const float* __restrict__ Wv, ushort* __restrict__ WT)
{
    __shared__ ushort lt[256 * 66];   // [k][d] padded
    const int t = threadIdx.x;
    const int m = blockIdx.x;
    const float* W = (m == 0) ? Wq : ((m == 1) ? Wk : Wv);
    const float scale = (m == 0) ? QSCALE : 1.0f;

    #pragma unroll
    for (int j = 0; j < 16; ++j) {
        int i4 = t + 256 * j;                 // float4 index
        float4 v = *(const float4*)&W[i4 * 4];
        int k = i4 >> 4, d = (i4 * 4) & 63;
        *(uint*)&lt[k * 66 + d]     = pk2(v.x * scale, v.y * scale);
        *(uint*)&lt[k * 66 + d + 2] = pk2(v.z * scale, v.w * scale);
    }
    __syncthreads();
    #pragma unroll
    for (int j = 0; j < 32; ++j) {            // uint (2-key) stores
        int o2 = t + 256 * j;
        int d = o2 >> 7, k = (o2 & 127) * 2;
        uint pk = (uint)lt[k * 66 + d] | ((uint)lt[(k + 1) * 66 + d] << 16);
        *(uint*)&WT[m * 16384 + d * 256 + k] = pk;
    }
}

// ---------------------------------------------------------------------------
// QKV: m-split grid (3 x rowblocks), 256 threads, 64 rows/block, 43KB LDS ->
// 3 blocks/CU. mb=0: Q row-major. mb=1/2: K/V written in FRAG-NATIVE PACKED
// layout (R8): attn load j reads lanes' 16B contiguously -> fully-coalesced
// sequential streams.
// ---------------------------------------------------------------------------
__global__ __launch_bounds__(256, 3) void qkv_kernel(
    const float* __restrict__ y, const ushort* __restrict__ WT,
    ushort* __restrict__ Qh, ushort* __restrict__ Kp, ushort* __restrict__ Vp,
    const int rbn)
{
    __shared__ ushort Wl[64 * 268];   // 34,304 B (pad 268: ~2-way banks)
    __shared__ ushort tb[64 * 68];    //  8,704 B

    const int t = threadIdx.x;
    const int w = t >> 6, lane = t & 63;
    const int quad = lane >> 4, l15 = lane & 15;
    const int mb = blockIdx.x / rbn;       // 0=Q 1=K 2=V
    const int rb = blockIdx.x % rbn;       // rowblock == (batch*64 + chunk64)
    const int rowbase = rb * 64;
    const int myrow = rowbase + w * 16 + l15;

    // ---- stage WT[mb] (32 KB): thread -> row n=t>>2, 128B segment ----
    {
        int n = t >> 2, seg = t & 3;
        const ushort* src = WT + mb * 16384 + n * 256 + seg * 64;
        ushort* dst = &Wl[n * 268 + seg * 64];
        #pragma unroll
        for (int j = 0; j < 16; ++j)
            ((uint2*)dst)[j] = ((const uint2*)src)[j];
    }

    // ---- A-fragments (overlap with staging loads) ----
    bf16x8 afrag[8];
    const float* yrow = y + (size_t)myrow * NINP;
    #pragma unroll
    for (int s = 0; s < 8; ++s) {
        float4 lo = *(const float4*)&yrow[s * 32 + quad * 8];
        float4 hi = *(const float4*)&yrow[s * 32 + quad * 8 + 4];
        U8 u;
        u.u[0] = pk2(lo.x, lo.y);
        u.u[1] = pk2(lo.z, lo.w);
        u.u[2] = pk2(hi.x, hi.y);
        u.u[3] = pk2(hi.z, hi.w);
        afrag[s] = u.v;
    }

    __syncthreads();

    f32x4 acc[4];
    #pragma unroll
    for (int nt = 0; nt < 4; ++nt) acc[nt] = f32x4{0.f, 0.f, 0.f, 0.f};

    #pragma unroll
    for (int s = 0; s < 8; ++s)
        #pragma unroll
        for (int nt = 0; nt < 4; ++nt) {
            bf16x8 bfrag = ld8x2(&Wl[(nt * 16 + l15) * 268 + s * 32 + quad * 8]);
            acc[nt] = __builtin_amdgcn_mfma_f32_16x16x32_bf16(
                afrag[s], bfrag, acc[nt], 0, 0, 0);
        }

    if (mb == 0) {
        // ---- Q row-major via LDS repack ----
        #pragma unroll
        for (int nt = 0; nt < 4; ++nt)
            #pragma unroll
            for (int r = 0; r < 4; ++r)
                tb[(w * 16 + quad * 4 + r) * 68 + nt * 16 + l15] = bfu(acc[nt][r]);
        __syncthreads();
        int row = t >> 2, seg = t & 3;
        ushort* gd = Qh + (size_t)(rowbase + row) * DD + seg * 16;
        const ushort* sp = &tb[row * 68 + seg * 16];
        #pragma unroll
        for (int j = 0; j < 4; ++j) ((uint2*)gd)[j] = ((const uint2*)sp)[j];
    } else if (mb == 1) {
        // ---- K packed: unit idx=(kt*2+s)*64+lane holds 16B of
        // K[row=kt*16+l15][d=s*32+quad*8..+7] ----
        #pragma unroll
        for (int nt = 0; nt < 4; ++nt)
            #pragma unroll
            for (int r = 0; r < 4; ++r)
                tb[(w * 16 + quad * 4 + r) * 68 + nt * 16 + l15] = bfu(acc[nt][r]);
        __syncthreads();
        #pragma unroll
        for (int j = 0; j < 2; ++j) {
            int idx = t + 256 * j;                 // 16B-unit 0..511
            int instr = idx >> 6, ln = idx & 63;
            int kt = instr >> 1, s = instr & 1;
            int q2 = ln >> 4, l15b = ln & 15;
            int row = kt * 16 + l15b, dcol = s * 32 + q2 * 8;
            const ushort* sp = &tb[row * 68 + dcol];
            ushort* gd = Kp + (size_t)rb * 4096 + idx * 8;
            ((uint2*)gd)[0] = ((const uint2*)sp)[0];
            ((uint2*)gd)[1] = ((const uint2*)sp)[1];
        }
    } else {
        // ---- V packed: unit idx=(nt*2+m)*64+lane holds two 8B halves
        // V^T[d=nt*16+l15][k=32m+16e+quad*4..+3], e=0,1 ----
        #pragma unroll
        for (int nt = 0; nt < 4; ++nt) {
            int d = nt * 16 + l15;
            #pragma unroll
            for (int r = 0; r < 4; r += 2) {
                int tt = w * 16 + quad * 4 + r;
                *(uint*)&tb[d * 68 + tt] = pk2(acc[nt][r], acc[nt][r + 1]);
            }
        }
        __syncthreads();
        #pragma unroll
        for (int j = 0; j < 2; ++j) {
            int idx = t + 256 * j;                 // 16B-unit 0..511
            int instr = idx >> 6, ln = idx & 63;
            int nt = instr >> 1, m = instr & 1;
            int q2 = ln >> 4, l15b = ln & 15;
            int d = nt * 16 + l15b;
            int k0 = 32 * m + q2 * 4;
            ushort* gd = Vp + (size_t)rb * 4096 + idx * 8;
            ((uint2*)gd)[0] = *(const uint2*)&tb[d * 68 + k0];
            ((uint2*)gd)[1] = *(const uint2*)&tb[d * 68 + k0 + 16];
        }
    }
}

// ===========================================================================
// Attention helpers (R10): 32-key chunks, packed layout (R8/R9).
// ===========================================================================
__device__ inline void load_k32(bf16x8 (&kf)[2][2], const ushort* __restrict__ Kw,
                                int ci)
{
    const ushort* base = Kw + (size_t)ci * 2048;
    #pragma unroll
    for (int kt = 0; kt < 2; ++kt)
        #pragma unroll
        for (int s = 0; s < 2; ++s)
            kf[kt][s] = ld16(base + (kt * 2 + s) * 512);
}

__device__ inline void load_v32(U4 (&vt)[4][2], const ushort* __restrict__ Vw,
                                int ci)
{
    const ushort* base = Vw + (size_t)(ci >> 1) * 4096 + (ci & 1) * 512;
    #pragma unroll
    for (int nt = 0; nt < 4; ++nt) {
        U8 uu; uu.v = ld16(base + nt * 1024);
        vt[nt][0].u[0] = uu.u[0]; vt[nt][0].u[1] = uu.u[1];
        vt[nt][1].u[0] = uu.u[2]; vt[nt][1].u[1] = uu.u[3];
    }
}

// ---------------------------------------------------------------------------
// Attention R10: 256 blocks x 768 threads (12 waves). Each block = complete
// snake PAIR (tile pr + 127-pr, 129 chunk-32s) -> perfectly uniform blocks,
// 1 block/CU (LDS 106KB), 3 waves/SIMD FLAT (R9's 2-blocks/CU was ragged:
// short co-resident block drained early -> effective ~2.5 and neutral).
// launch_bounds (768,2): allocator unconstrained (R5/R7 lesson); LDS already
// caps at 1 block. 12-way key-seg split: wave w does seg w of pr, seg 11-w
// of 127-pr -> critical path ~11 chunks/wave. P packed via v_cvt_pk_bf16_f32
// (non-RNE, but P-only: O = sum(pv)/sum(p) is scale-invariant -> truncation
// bias cancels; Q/K/V/W stay RNE). XCD-batch clustering: batch=(id&7)>>1.
// S^T = K.Q^T (16x16x32); P in registers (S^T lane layout == B-operand of
// mfma_f32_16x16x16_bf16) -> O^T = V^T.P^T, no LDS transpose.
// ---------------------------------------------------------------------------
__global__ __launch_bounds__(768, 2) void attn_kernel(
    const ushort* __restrict__ Qh, const ushort* __restrict__ Kp,
    const ushort* __restrict__ Vp, float* __restrict__ out)
{
    __shared__ float Ob[12][32 * 68];   // per-wave partial O [q][d] padded
    __shared__ float lb[12][32];        // per-wave partial l

    const int t = threadIdx.x;
    const int w = t >> 6, lane = t & 63;
    const int quad = lane >> 4, l15 = lane & 15;

    // XCD-clustered decode (grid = 256 = 4 batches x 64 pairs)
    const int x  = blockIdx.x & 7;
    const int b  = x >> 1;
    const int pr = (((int)blockIdx.x >> 3) << 1) | (x & 1);   // 0..63

    const ushort* Qb = Qh + (size_t)b * TLEN * DD;
    const ushort* Kw = Kp + (size_t)b * 64 * 4096 + lane * 8;
    const ushort* Vw = Vp + (size_t)b * 64 * 4096 + lane * 8;
    float* outb = out + (size_t)b * TLEN * DD;

    for (int half = 0; half < 2; ++half) {
        const int tile = half ? (127 - pr) : pr;
        const int seg  = half ? (11 - w) : w;
        const int qb   = tile * 32;
        const int nc   = tile + 1;                    // 32-key chunks
        const int cps  = (nc + 11) / 12;
        const int clo  = seg * cps;
        const int chi  = (nc < clo + cps) ? nc : (clo + cps);

        f32x4 oT[2][4];                  // O^T: d=nt*16+quad*4+r, q=qb+qt*16+l15
        #pragma unroll
        for (int qt = 0; qt < 2; ++qt)
            #pragma unroll
            for (int nt = 0; nt < 4; ++nt)
                oT[qt][nt] = f32x4{0.f, 0.f, 0.f, 0.f};
        float l_acc[2] = {0.f, 0.f};

        if (clo < chi) {
            // Q B-frags (fixed per tile)
            bf16x8 qf[2][2];
            #pragma unroll
            for (int qt = 0; qt < 2; ++qt)
                #pragma unroll
                for (int s = 0; s < 2; ++s)
                    qf[qt][s] = ld16(Qb + (size_t)(qb + qt * 16 + l15) * DD + s * 32 + quad * 8);

            // K prefetch for first chunk
            bf16x8 kf[2][2];
            load_k32(kf, Kw, clo);

            for (int ci = clo; ci < chi; ++ci) {
                const int c0 = ci * 32;

                // V frags (packed, coalesced; used ~end of body)
                U4 vt[4][2];
                load_v32(vt, Vw, ci);

                // S^T = K·Q^T
                f32x4 st[2][2];
                #pragma unroll
                for (int qt = 0; qt < 2; ++qt)
                    #pragma unroll
                    for (int kt = 0; kt < 2; ++kt)
                        st[qt][kt] = f32x4{0.f, 0.f, 0.f, 0.f};
                __builtin_amdgcn_s_setprio(1);
                #pragma unroll
                for (int s = 0; s < 2; ++s)
                    #pragma unroll
                    for (int qt = 0; qt < 2; ++qt)
                        #pragma unroll
                        for (int kt = 0; kt < 2; ++kt)
                            st[qt][kt] = __builtin_amdgcn_mfma_f32_16x16x32_bf16(
                                kf[kt][s], qf[qt][s], st[qt][kt], 0, 0, 0);
                __builtin_amdgcn_s_setprio(0);

                // prefetch next chunk's K frags
                if (ci + 1 < chi) load_k32(kf, Kw, ci + 1);

                // softmax weights -> bf16 P^T frags (cvt_pk; bias cancels in O)
                U4 pa[2][2];
                if (c0 + 31 <= qb) {            // wave-uniform: unmasked chunk
                    #pragma unroll
                    for (int qt = 0; qt < 2; ++qt)
                        #pragma unroll
                        for (int kt = 0; kt < 2; ++kt) {
                            float p0 = exp2f(st[qt][kt][0]);
                            float p1 = exp2f(st[qt][kt][1]);
                            float p2 = exp2f(st[qt][kt][2]);
                            float p3 = exp2f(st[qt][kt][3]);
                            l_acc[qt] += (p0 + p1) + (p2 + p3);
                            pa[qt][kt].u[0] = cvtpk(p0, p1);
                            pa[qt][kt].u[1] = cvtpk(p2, p3);
                        }
                } else {                        // diagonal chunk: causal mask
                    #pragma unroll
                    for (int qt = 0; qt < 2; ++qt) {
                        const int q = qb + qt * 16 + l15;
                        #pragma unroll
                        for (int kt = 0; kt < 2; ++kt) {
                            const int kb0 = c0 + kt * 16 + quad * 4;
                            float p[4];
                            #pragma unroll
                            for (int r = 0; r < 4; ++r) {
                                float e = exp2f(st[qt][kt][r]);
                                p[r] = (kb0 + r <= q) ? e : 0.f;
                                l_acc[qt] += p[r];
                            }
                            pa[qt][kt].u[0] = cvtpk(p[0], p[1]);
                            pa[qt][kt].u[1] = cvtpk(p[2], p[3]);
                        }
                    }
                }

                // O^T += V^T·P^T (16x16x16, K=16: B-layout == S^T lane layout)
                __builtin_amdgcn_s_setprio(1);
                #pragma unroll
                for (int qt = 0; qt < 2; ++qt)
                    #pragma unroll
                    for (int nt = 0; nt < 4; ++nt)
                        #pragma unroll
                        for (int kt = 0; kt < 2; ++kt)
                            oT[qt][nt] = __builtin_amdgcn_mfma_f32_16x16x16bf16_1k(
                                vt[nt][kt].v, pa[qt][kt].v, oT[qt][nt], 0, 0, 0);
                __builtin_amdgcn_s_setprio(0);
            }

            // reduce l across quads (keys live in quads)
            #pragma unroll
            for (int qt = 0; qt < 2; ++qt) {
                l_acc[qt] += __shfl_xor(l_acc[qt], 16, 64);
                l_acc[qt] += __shfl_xor(l_acc[qt], 32, 64);
            }
        }

        // publish partials (zeros if empty task)
        #pragma unroll
        for (int qt = 0; qt < 2; ++qt) {
            #pragma unroll
            for (int nt = 0; nt < 4; ++nt)
                #pragma unroll
                for (int r = 0; r < 4; ++r)
                    Ob[w][(qt * 16 + l15) * 68 + nt * 16 + quad * 4 + r] = oT[qt][nt][r];
            if (quad == 0) lb[w][qt * 16 + l15] = l_acc[qt];
        }
        __syncthreads();

        // in-block combine + store (complete: all 12 segs of this tile here)
        #pragma unroll
        for (int e = 0; e < 3; ++e) {
            int idx = t + 768 * e;
            if (idx < 2048) {
                int q = idx >> 6, d = idx & 63;
                float s = 0.f, ls = 0.f;
                #pragma unroll
                for (int ww = 0; ww < 12; ++ww) {
                    s += Ob[ww][q * 68 + d];
                    ls += lb[ww][q];
                }
                outb[(size_t)(qb + q) * DD + d] = s * __builtin_amdgcn_rcpf(ls);
            }
        }
        __syncthreads();
    }
}

extern "C" void kernel_launch(void* const* d_in, const int* in_sizes, int n_in,
                              void* d_out, int out_size, void* d_ws, size_t ws_size,
                              hipStream_t stream) {
    const float* y  = (const float*)d_in[0];
    const float* Wq = (const float*)d_in[1];
    const float* Wk = (const float*)d_in[2];
    const float* Wv = (const float*)d_in[3];
    float* outp = (float*)d_out;

    const int rows = in_sizes[0] / NINP;       // B*T = 16384
    const int nb = rows / TLEN;                // batches = 4
    const int rbn = rows / 64;                 // 256 row-blocks

    ushort* WT = (ushort*)d_ws;                // 3*16384 bf16 = 96 KB
    ushort* Qh = WT + 3 * 16384;               // rows*64 bf16 = 2 MB
    ushort* Kp = Qh + (size_t)rows * DD;       // packed K: rb*4096 units
    ushort* Vp = Kp + (size_t)rows * DD;       // packed V: rb*4096 units

    prep_wt<<<3, 256, 0, stream>>>(Wq, Wk, Wv, WT);
    qkv_kernel<<<3 * rbn, 256, 0, stream>>>(y, WT, Qh, Kp, Vp, rbn);
    attn_kernel<<<nb * 64, 768, 0, stream>>>(Qh, Kp, Vp, outp);
}

// Round 11
// 100.346 us; speedup vs baseline: 1.3688x; 1.0109x over previous
//
#include <hip/hip_runtime.h>
#include <hip/hip_bf16.h>

#define TLEN 4096
#define NINP 256
#define DD   64

// 1/sqrt(64) * log2(e): folded into WqT so softmax = exp2(s)
#define QSCALE 0.18033688011112042f

typedef __attribute__((ext_vector_type(8))) short bf16x8;
typedef __attribute__((ext_vector_type(4))) short bf16x4;
typedef __attribute__((ext_vector_type(4))) float f32x4;

union U8 { bf16x8 v; uint u[4]; };
union U4 { bf16x4 v; uint u[2]; };

// fp32 -> bf16 RNE (manual; v_cvt_pk_bf16_f32 is NOT RNE -> used only where
// bias is cancelled: P-weights, numerator AND denominator)
__device__ inline ushort bfu(float x) {
    union { float f; uint u; } a; a.f = x;
    uint r = a.u + 0x7fffu + ((a.u >> 16) & 1u);
    return (ushort)(r >> 16);
}
__device__ inline uint pk2(float lo, float hi) {
    return (uint)bfu(lo) | ((uint)bfu(hi) << 16);
}
// hardware packed cvt (non-RNE): P-only (scale-invariance cancels bias)
__device__ inline uint cvtpk(float lo, float hi) {
    uint r;
    asm("v_cvt_pk_bf16_f32 %0, %1, %2" : "=v"(r) : "v"(lo), "v"(hi));
    return r;
}

__device__ inline bf16x8 ld16(const ushort* p) {  // 16B-aligned global/LDS
    return *(const bf16x8*)p;
}

// ---------------------------------------------------------------------------
// prep: WTf[m] in FRAG-NATIVE layout (R11): unit u=(s*4+nt), slot = u*64+lane,
// 16B at slot*8 = W^T[d=nt*16+(lane&15)][k=s*32+(lane>>4)*8 .. +7], Wq scaled.
// qkv then loads B-fragments as single coalesced ld16 (1KB/instr) -> no LDS
// staging in qkv at all.
// ---------------------------------------------------------------------------
__global__ __launch_bounds__(256) void prep_wt(
    const float* __restrict__ Wq, const float* __restrict__ Wk,
    const float* __restrict__ Wv, ushort* __restrict__ WTf)
{
    __shared__ ushort lt[256 * 66];   // [k][d] padded
    const int t = threadIdx.x;
    const int m = blockIdx.x;
    const float* W = (m == 0) ? Wq : ((m == 1) ? Wk : Wv);
    const float scale = (m == 0) ? QSCALE : 1.0f;

    #pragma unroll
    for (int j = 0; j < 16; ++j) {
        int i4 = t + 256 * j;                 // float4 index
        float4 v = *(const float4*)&W[i4 * 4];
        int k = i4 >> 4, d = (i4 * 4) & 63;
        *(uint*)&lt[k * 66 + d]     = pk2(v.x * scale, v.y * scale);
        *(uint*)&lt[k * 66 + d + 2] = pk2(v.z * scale, v.w * scale);
    }
    __syncthreads();
    #pragma unroll
    for (int j = 0; j < 8; ++j) {
        int slot = t + 256 * j;               // 2048 slots x 8 ushort
        int u = slot >> 6, ln = slot & 63;
        int s = u >> 2, nt = u & 3;
        int d = nt * 16 + (ln & 15);
        int k0 = s * 32 + (ln >> 4) * 8;
        uint a0 = (uint)lt[(k0 + 0) * 66 + d] | ((uint)lt[(k0 + 1) * 66 + d] << 16);
        uint a1 = (uint)lt[(k0 + 2) * 66 + d] | ((uint)lt[(k0 + 3) * 66 + d] << 16);
        uint a2 = (uint)lt[(k0 + 4) * 66 + d] | ((uint)lt[(k0 + 5) * 66 + d] << 16);
        uint a3 = (uint)lt[(k0 + 6) * 66 + d] | ((uint)lt[(k0 + 7) * 66 + d] << 16);
        ushort* gd = WTf + m * 16384 + slot * 8;
        ((uint2*)gd)[0] = uint2{a0, a1};
        ((uint2*)gd)[1] = uint2{a2, a3};
    }
}

// ---------------------------------------------------------------------------
// QKV (R11): m-split grid (3 x rowblocks), 256 threads, 64 rows/block.
// NO W staging: B-fragments load directly from frag-native WTf (L1/L2-hit,
// coalesced ld16) -> drops 32KB LDS + staging loop + one barrier. LDS = tb
// only (8.7KB). mb=0: Q row-major. mb=1/2: K/V packed (R8 frag-native).
// ---------------------------------------------------------------------------
__global__ __launch_bounds__(256) void qkv_kernel(
    const float* __restrict__ y, const ushort* __restrict__ WTf,
    ushort* __restrict__ Qh, ushort* __restrict__ Kp, ushort* __restrict__ Vp,
    const int rbn)
{
    __shared__ ushort tb[64 * 68];    //  8,704 B

    const int t = threadIdx.x;
    const int w = t >> 6, lane = t & 63;
    const int quad = lane >> 4, l15 = lane & 15;
    const int mb = blockIdx.x / rbn;       // 0=Q 1=K 2=V
    const int rb = blockIdx.x % rbn;       // rowblock == (batch*64 + chunk64)
    const int rowbase = rb * 64;
    const int myrow = rowbase + w * 16 + l15;

    // ---- A-fragments ----
    bf16x8 afrag[8];
    const float* yrow = y + (size_t)myrow * NINP;
    #pragma unroll
    for (int s = 0; s < 8; ++s) {
        float4 lo = *(const float4*)&yrow[s * 32 + quad * 8];
        float4 hi = *(const float4*)&yrow[s * 32 + quad * 8 + 4];
        U8 u;
        u.u[0] = pk2(lo.x, lo.y);
        u.u[1] = pk2(lo.z, lo.w);
        u.u[2] = pk2(hi.x, hi.y);
        u.u[3] = pk2(hi.z, hi.w);
        afrag[s] = u.v;
    }

    f32x4 acc[4];
    #pragma unroll
    for (int nt = 0; nt < 4; ++nt) acc[nt] = f32x4{0.f, 0.f, 0.f, 0.f};

    const ushort* Wm = WTf + mb * 16384 + lane * 8;
    #pragma unroll
    for (int s = 0; s < 8; ++s)
        #pragma unroll
        for (int nt = 0; nt < 4; ++nt) {
            bf16x8 bfrag = ld16(Wm + (s * 4 + nt) * 512);
            acc[nt] = __builtin_amdgcn_mfma_f32_16x16x32_bf16(
                afrag[s], bfrag, acc[nt], 0, 0, 0);
        }

    if (mb == 0) {
        // ---- Q row-major via LDS repack ----
        #pragma unroll
        for (int nt = 0; nt < 4; ++nt)
            #pragma unroll
            for (int r = 0; r < 4; ++r)
                tb[(w * 16 + quad * 4 + r) * 68 + nt * 16 + l15] = bfu(acc[nt][r]);
        __syncthreads();
        int row = t >> 2, seg = t & 3;
        ushort* gd = Qh + (size_t)(rowbase + row) * DD + seg * 16;
        const ushort* sp = &tb[row * 68 + seg * 16];
        #pragma unroll
        for (int j = 0; j < 4; ++j) ((uint2*)gd)[j] = ((const uint2*)sp)[j];
    } else if (mb == 1) {
        // ---- K packed: unit idx=(kt*2+s)*64+lane holds 16B of
        // K[row=kt*16+l15][d=s*32+quad*8..+7] ----
        #pragma unroll
        for (int nt = 0; nt < 4; ++nt)
            #pragma unroll
            for (int r = 0; r < 4; ++r)
                tb[(w * 16 + quad * 4 + r) * 68 + nt * 16 + l15] = bfu(acc[nt][r]);
        __syncthreads();
        #pragma unroll
        for (int j = 0; j < 2; ++j) {
            int idx = t + 256 * j;                 // 16B-unit 0..511
            int instr = idx >> 6, ln = idx & 63;
            int kt = instr >> 1, s = instr & 1;
            int q2 = ln >> 4, l15b = ln & 15;
            int row = kt * 16 + l15b, dcol = s * 32 + q2 * 8;
            const ushort* sp = &tb[row * 68 + dcol];
            ushort* gd = Kp + (size_t)rb * 4096 + idx * 8;
            ((uint2*)gd)[0] = ((const uint2*)sp)[0];
            ((uint2*)gd)[1] = ((const uint2*)sp)[1];
        }
    } else {
        // ---- V packed: unit idx=(nt*2+m)*64+lane holds two 8B halves
        // V^T[d=nt*16+l15][k=32m+16e+quad*4..+3], e=0,1 ----
        #pragma unroll
        for (int nt = 0; nt < 4; ++nt) {
            int d = nt * 16 + l15;
            #pragma unroll
            for (int r = 0; r < 4; r += 2) {
                int tt = w * 16 + quad * 4 + r;
                *(uint*)&tb[d * 68 + tt] = pk2(acc[nt][r], acc[nt][r + 1]);
            }
        }
        __syncthreads();
        #pragma unroll
        for (int j = 0; j < 2; ++j) {
            int idx = t + 256 * j;                 // 16B-unit 0..511
            int instr = idx >> 6, ln = idx & 63;
            int nt = instr >> 1, m = instr & 1;
            int q2 = ln >> 4, l15b = ln & 15;
            int d = nt * 16 + l15b;
            int k0 = 32 * m + q2 * 4;
            ushort* gd = Vp + (size_t)rb * 4096 + idx * 8;
            ((uint2*)gd)[0] = *(const uint2*)&tb[d * 68 + k0];
            ((uint2*)gd)[1] = *(const uint2*)&tb[d * 68 + k0 + 16];
        }
    }
}

// ===========================================================================
// Attention helpers: 32-key chunks, packed layout. R11: K prefetch 2-DEEP
// (ping-pong kfA/kfB, +16 VGPR only at chunk-32 size -> ~150 total, fits the
// 170 cap that 12-wave residency implies; R7's spill was chunk-64 +64 regs).
// ===========================================================================
__device__ inline void load_k32(bf16x8 (&kf)[2][2], const ushort* __restrict__ Kw,
                                int ci)
{
    const ushort* base = Kw + (size_t)ci * 2048;
    #pragma unroll
    for (int kt = 0; kt < 2; ++kt)
        #pragma unroll
        for (int s = 0; s < 2; ++s)
            kf[kt][s] = ld16(base + (kt * 2 + s) * 512);
}

__device__ inline void load_v32(U4 (&vt)[4][2], const ushort* __restrict__ Vw,
                                int ci)
{
    const ushort* base = Vw + (size_t)(ci >> 1) * 4096 + (ci & 1) * 512;
    #pragma unroll
    for (int nt = 0; nt < 4; ++nt) {
        U8 uu; uu.v = ld16(base + nt * 1024);
        vt[nt][0].u[0] = uu.u[0]; vt[nt][0].u[1] = uu.u[1];
        vt[nt][1].u[0] = uu.u[2]; vt[nt][1].u[1] = uu.u[3];
    }
}

// one 32-key chunk: compute with kf, prefetch chunk `pf` into kfn (own buffer)
__device__ inline void chunk32(
    const bf16x8 (&kf)[2][2], bf16x8 (&kfn)[2][2],
    const ushort* __restrict__ Kw, const ushort* __restrict__ Vw,
    const bf16x8 (&qf)[2][2], f32x4 (&oT)[2][4], float (&l_acc)[2],
    int ci, int pf, int chi, int qb, int quad, int l15)
{
    const int c0 = ci * 32;
    U4 vt[4][2];
    load_v32(vt, Vw, ci);

    // S^T = K·Q^T
    f32x4 st[2][2];
    #pragma unroll
    for (int qt = 0; qt < 2; ++qt)
        #pragma unroll
        for (int kt = 0; kt < 2; ++kt)
            st[qt][kt] = f32x4{0.f, 0.f, 0.f, 0.f};
    __builtin_amdgcn_s_setprio(1);
    #pragma unroll
    for (int s = 0; s < 2; ++s)
        #pragma unroll
        for (int qt = 0; qt < 2; ++qt)
            #pragma unroll
            for (int kt = 0; kt < 2; ++kt)
                st[qt][kt] = __builtin_amdgcn_mfma_f32_16x16x32_bf16(
                    kf[kt][s], qf[qt][s], st[qt][kt], 0, 0, 0);
    __builtin_amdgcn_s_setprio(0);

    // prefetch 2-ahead into own buffer (reads of kf already consumed)
    if (pf < chi) load_k32(kfn, Kw, pf);

    // softmax weights -> bf16 P^T frags (cvt_pk; bias cancels in O)
    U4 pa[2][2];
    if (c0 + 31 <= qb) {            // wave-uniform: fully unmasked chunk
        #pragma unroll
        for (int qt = 0; qt < 2; ++qt)
            #pragma unroll
            for (int kt = 0; kt < 2; ++kt) {
                float p0 = exp2f(st[qt][kt][0]);
                float p1 = exp2f(st[qt][kt][1]);
                float p2 = exp2f(st[qt][kt][2]);
                float p3 = exp2f(st[qt][kt][3]);
                l_acc[qt] += (p0 + p1) + (p2 + p3);
                pa[qt][kt].u[0] = cvtpk(p0, p1);
                pa[qt][kt].u[1] = cvtpk(p2, p3);
            }
    } else {                        // diagonal chunk: causal mask
        #pragma unroll
        for (int qt = 0; qt < 2; ++qt) {
            const int q = qb + qt * 16 + l15;
            #pragma unroll
            for (int kt = 0; kt < 2; ++kt) {
                const int kb0 = c0 + kt * 16 + quad * 4;
                float p[4];
                #pragma unroll
                for (int r = 0; r < 4; ++r) {
                    float e = exp2f(st[qt][kt][r]);
                    p[r] = (kb0 + r <= q) ? e : 0.f;
                    l_acc[qt] += p[r];
                }
                pa[qt][kt].u[0] = cvtpk(p[0], p[1]);
                pa[qt][kt].u[1] = cvtpk(p[2], p[3]);
            }
        }
    }

    // O^T += V^T·P^T (16x16x16, K=16: B-layout == S^T lane layout)
    __builtin_amdgcn_s_setprio(1);
    #pragma unroll
    for (int qt = 0; qt < 2; ++qt)
        #pragma unroll
        for (int nt = 0; nt < 4; ++nt)
            #pragma unroll
            for (int kt = 0; kt < 2; ++kt)
                oT[qt][nt] = __builtin_amdgcn_mfma_f32_16x16x16bf16_1k(
                    vt[nt][kt].v, pa[qt][kt].v, oT[qt][nt], 0, 0, 0);
    __builtin_amdgcn_s_setprio(0);
}

// ---------------------------------------------------------------------------
// Attention R11: 256 blocks x 768 threads (12 waves, 1 block/CU, 3 waves/SIMD
// flat; R10 structure). Block = complete snake pair (129 chunk-32s uniform),
// 12-way key-seg split. K prefetch 2-deep ping-pong (kfA/kfB). V 1-deep
// (full-body cover already). P via cvt_pk (bias cancels). XCD-batch
// clustering: batch=(id&7)>>1 -> K+V per XCD pair L2-resident.
// launch_bounds (768,3): states the true residency (12 waves = 3/EU) -> cap
// 170 VGPR, guaranteed schedulable.
// ---------------------------------------------------------------------------
__global__ __launch_bounds__(768, 3) void attn_kernel(
    const ushort* __restrict__ Qh, const ushort* __restrict__ Kp,
    const ushort* __restrict__ Vp, float* __restrict__ out)
{
    __shared__ float Ob[12][32 * 68];   // per-wave partial O [q][d] padded
    __shared__ float lb[12][32];        // per-wave partial l

    const int t = threadIdx.x;
    const int w = t >> 6, lane = t & 63;
    const int quad = lane >> 4, l15 = lane & 15;

    // XCD-clustered decode (grid = 256 = 4 batches x 64 pairs)
    const int x  = blockIdx.x & 7;
    const int b  = x >> 1;
    const int pr = (((int)blockIdx.x >> 3) << 1) | (x & 1);   // 0..63

    const ushort* Qb = Qh + (size_t)b * TLEN * DD;
    const ushort* Kw = Kp + (size_t)b * 64 * 4096 + lane * 8;
    const ushort* Vw = Vp + (size_t)b * 64 * 4096 + lane * 8;
    float* outb = out + (size_t)b * TLEN * DD;

    for (int half = 0; half < 2; ++half) {
        const int tile = half ? (127 - pr) : pr;
        const int seg  = half ? (11 - w) : w;
        const int qb   = tile * 32;
        const int nc   = tile + 1;                    // 32-key chunks
        const int cps  = (nc + 11) / 12;
        const int clo  = seg * cps;
        const int chi  = (nc < clo + cps) ? nc : (clo + cps);

        f32x4 oT[2][4];                  // O^T: d=nt*16+quad*4+r, q=qb+qt*16+l15
        #pragma unroll
        for (int qt = 0; qt < 2; ++qt)
            #pragma unroll
            for (int nt = 0; nt < 4; ++nt)
                oT[qt][nt] = f32x4{0.f, 0.f, 0.f, 0.f};
        float l_acc[2] = {0.f, 0.f};

        if (clo < chi) {
            // Q B-frags (fixed per tile)
            bf16x8 qf[2][2];
            #pragma unroll
            for (int qt = 0; qt < 2; ++qt)
                #pragma unroll
                for (int s = 0; s < 2; ++s)
                    qf[qt][s] = ld16(Qb + (size_t)(qb + qt * 16 + l15) * DD + s * 32 + quad * 8);

            // K ping-pong prologue: A <- clo, B <- clo+1
            bf16x8 kfA[2][2], kfB[2][2];
            load_k32(kfA, Kw, clo);
            if (clo + 1 < chi) load_k32(kfB, Kw, clo + 1);

            for (int ci = clo; ci < chi; ci += 2) {
                chunk32(kfA, kfA, Kw, Vw, qf, oT, l_acc,
                        ci, ci + 2, chi, qb, quad, l15);
                if (ci + 1 < chi)
                    chunk32(kfB, kfB, Kw, Vw, qf, oT, l_acc,
                            ci + 1, ci + 3, chi, qb, quad, l15);
            }

            // reduce l across quads (keys live in quads)
            #pragma unroll
            for (int qt = 0; qt < 2; ++qt) {
                l_acc[qt] += __shfl_xor(l_acc[qt], 16, 64);
                l_acc[qt] += __shfl_xor(l_acc[qt], 32, 64);
            }
        }

        // publish partials (zeros if empty task)
        #pragma unroll
        for (int qt = 0; qt < 2; ++qt) {
            #pragma unroll
            for (int nt = 0; nt < 4; ++nt)
                #pragma unroll
                for (int r = 0; r < 4; ++r)
                    Ob[w][(qt * 16 + l15) * 68 + nt * 16 + quad * 4 + r] = oT[qt][nt][r];
            if (quad == 0) lb[w][qt * 16 + l15] = l_acc[qt];
        }
        __syncthreads();

        // in-block combine + store (complete: all 12 segs of this tile here)
        #pragma unroll
        for (int e = 0; e < 3; ++e) {
            int idx = t + 768 * e;
            if (idx < 2048) {
                int q = idx >> 6, d = idx & 63;
                float s = 0.f, ls = 0.f;
                #pragma unroll
                for (int ww = 0; ww < 12; ++ww) {
                    s += Ob[ww][q * 68 + d];
                    ls += lb[ww][q];
                }
                outb[(size_t)(qb + q) * DD + d] = s * __builtin_amdgcn_rcpf(ls);
            }
        }
        __syncthreads();
    }
}

extern "C" void kernel_launch(void* const* d_in, const int* in_sizes, int n_in,
                              void* d_out, int out_size, void* d_ws, size_t ws_size,
                              hipStream_t stream) {
    const float* y  = (const float*)d_in[0];
    const float* Wq = (const float*)d_in[1];
    const float* Wk = (const float*)d_in[2];
    const float* Wv = (const float*)d_in[3];
    float* outp = (float*)d_out;

    const int rows = in_sizes[0] / NINP;       // B*T = 16384
    const int nb = rows / TLEN;                // batches = 4
    const int rbn = rows / 64;                 // 256 row-blocks

    ushort* WT = (ushort*)d_ws;                // 3*16384 bf16 = 96 KB (frag-native)
    ushort* Qh = WT + 3 * 16384;               // rows*64 bf16 = 2 MB
    ushort* Kp = Qh + (size_t)rows * DD;       // packed K: rb*4096 units
    ushort* Vp = Kp + (size_t)rows * DD;       // packed V: rb*4096 units

    prep_wt<<<3, 256, 0, stream>>>(Wq, Wk, Wv, WT);
    qkv_kernel<<<3 * rbn, 256, 0, stream>>>(y, WT, Qh, Kp, Vp, rbn);
    attn_kernel<<<nb * 64, 768, 0, stream>>>(Qh, Kp, Vp, outp);
}